// Round 5
// baseline (13160.188 us; speedup 1.0000x reference)
//
#include <hip/hip_runtime.h>
#include <cfloat>
#include <math.h>

#define N 512
typedef unsigned long long u64_t;

__device__ __forceinline__ u64_t map_f64(double x) {
    u64_t b = (u64_t)__double_as_longlong(x);
    return b ^ ((b >> 63) ? 0xFFFFFFFFFFFFFFFFull : 0x8000000000000000ull);
}
__device__ __forceinline__ double unmap_f64(u64_t b) {
    b ^= ((b >> 63) ? 0x8000000000000000ull : 0xFFFFFFFFFFFFFFFFull);
    return __longlong_as_double((long long)b);
}

// wave64 u64 min-reduce via DPP (VALU pipe). Valid result in lane 63.
__device__ __forceinline__ u64_t wave_min_key(u64_t key) {
    unsigned hi = (unsigned)(key >> 32), lo = (unsigned)key;
#define MIN_STAGE(CTRL)                                                        \
    {                                                                          \
        unsigned oh = (unsigned)__builtin_amdgcn_update_dpp((int)hi, (int)hi,  \
                                                            CTRL, 0xF, 0xF, false); \
        unsigned ol = (unsigned)__builtin_amdgcn_update_dpp((int)lo, (int)lo,  \
                                                            CTRL, 0xF, 0xF, false); \
        const u64_t o = ((u64_t)oh << 32) | ol;                                \
        const u64_t c = ((u64_t)hi << 32) | lo;                                \
        if (o < c) { hi = oh; lo = ol; }                                       \
    }
    MIN_STAGE(0x111) MIN_STAGE(0x112) MIN_STAGE(0x114) MIN_STAGE(0x118)
    MIN_STAGE(0x142) MIN_STAGE(0x143)
#undef MIN_STAGE
    return ((u64_t)hi << 32) | lo;
}

// Exact JV. Phases:
//  - column reduction + greedy tight match + LAPJV ARR warm start: 512 thr / 8 waves
//    (unchanged from R4 baseline).
//  - Dijkstra: SINGLE WAVE, 8 columns/lane, zero __syncthreads. R1-R4 measured the
//    8-wave Dijkstra interval at ~1050cy dominated by barrier+slot+atomic+skew
//    (VALU trims were neutral); one wave is lockstep: combine = lane-local min(8)
//    -> DPP wave-min -> readlane(63). Identical key set => bit-identical winners.
//  - f32 conservative filter (ptf/uf mirrors, slack 1e-4 >> f32 err ~3e-6): passing
//    lanes re-test in exact f64 => updates bit-identical (filter only prunes).
//  - absolute dist labels + epilogue dual settlement (R4, verified absmax 0).
// key = [45b value | 9b col-1 | 10b p[col]] (truncation precedent: absmax 0).
__global__ __launch_bounds__(512, 1) void tofu_solver(
    const float* __restrict__ dgm, const float* __restrict__ dgm_x,
    float* __restrict__ out)
{
#pragma clang fp contract(off)
    __shared__ double2 pt[N];
    __shared__ float2  ptf[N];
    __shared__ double  u_lds[N + 1];
    __shared__ float   uf[N + 1];
    __shared__ double  vj_lds[N + 1];
    __shared__ int     p_lds[N + 1];
    __shared__ int     way_lds[N + 1];
    __shared__ int     claim[N + 1];
    __shared__ int     flist[4 * N + 32];
    __shared__ u64_t   aslot[2], bslot[2];  // ARR slots (parity)
    __shared__ double  v1x;
    __shared__ double  red8[8];
    __shared__ int     nfree_s;

    const int tid  = threadIdx.x;       // 0..511
    const int col  = tid + 1;           // 1..512
    const int lane = tid & 63;
    const int wid  = tid >> 6;
    const float2* dgm2  = (const float2*)dgm;
    const float2* dgmx2 = (const float2*)dgm_x;

    // ---- stage points; own column's target point in registers ----
    {
        const float2 p2 = dgm2[tid];
        pt[tid]  = make_double2((double)p2.x, (double)p2.y);
        ptf[tid] = p2;
    }
    const float2 q2 = dgmx2[tid];
    const double xb = (double)q2.x, xd = (double)q2.y;
    u_lds[col] = 0.0; p_lds[col] = 0; way_lds[col] = 0; claim[col] = 0x7fffffff;
    if (tid == 0) {
        u_lds[0] = 0.0; p_lds[0] = 0; way_lds[0] = 0; claim[0] = 0x7fffffff;
        aslot[0] = aslot[1] = ~0ull; bslot[0] = bslot[1] = ~0ull;
    }
    __syncthreads();

    // ---- column reduction: argmin over squared dist (sqrt monotone => same v) ----
    double v_j; int amin;
    {
        double vsq = DBL_MAX; amin = 1;
        for (int i = 0; i < N; ++i) {
            const double2 rp = pt[i];                 // broadcast b128
            const double db = rp.x - xb, dd = rp.y - xd;
            const double sq = db * db + dd * dd;
            if (sq < vsq) { vsq = sq; amin = i + 1; }
        }
        v_j = sqrt(vsq);                              // exact: sqrt(min) == min(sqrt)
    }

    // ---- greedy tight matching: row r -> smallest col whose argmin is r ----
    atomicMin(&claim[amin], col);
    __syncthreads();
    if (claim[amin] == col) p_lds[col] = amin;        // tight: c=v[col], u=0
    __syncthreads();
    // freelist of unmatched rows
    claim[col] = 0;
    __syncthreads();
    { const int r = p_lds[col]; if (r) claim[r] = 1; }
    __syncthreads();
    if (tid == 0) {
        int nf = 0;
        for (int r = 1; r <= N; ++r) if (!claim[r]) flist[nf++] = r;
        nfree_s = nf;
    }
    __syncthreads();

    // ---- LAPJV augmenting row reduction (exactness-preserving, capped) ----
    {
        int head = 0, tail = nfree_s, q = 0;
        const int cap = 3 * tail + 16;
        int myp = p_lds[col];                          // register copy of p[col]
        for (int step = 0; step < cap && head < tail; ++step) {
            const int i = flist[head++];               // uniform broadcast
            const double2 rp = pt[i - 1];
            const double db = rp.x - xb, dd = rp.y - xd;
            const double val = sqrt(db * db + dd * dd) - v_j;   // exact f64
            const u64_t key = (map_f64(val) & ~0x7FFFFull)
                            | ((u64_t)(col - 1) << 10) | (u64_t)myp;
            u64_t kr = wave_min_key(key);
            if (lane == 63) atomicMin(&aslot[q], kr);
            __syncthreads();                           // barrier 1
            const u64_t k1 = aslot[q];
            const int j1    = (int)((k1 >> 10) & 511) + 1;
            const int k_old = (int)(k1 & 1023);
            if (col == j1) v1x = val;                  // exact v1 handoff
            kr = wave_min_key((col == j1) ? ~0ull : key);
            if (lane == 63) atomicMin(&bslot[q], kr);
            __syncthreads();                           // barrier 2
            const double m2t = unmap_f64(bslot[q] & ~0x7FFFFull);  // <= true 2nd-min
            const double v1e = v1x;
            const double ui  = fmax(m2t, v1e);         // feasible AND tight on j1
            if (col == j1) { v_j -= (ui - val); myp = i; }
            if (tid == 0) {
                u_lds[i] = ui;
                p_lds[j1] = i;
                if (k_old) flist[tail] = k_old;
                aslot[q ^ 1] = ~0ull; bslot[q ^ 1] = ~0ull;  // safe: 2 barriers since last read
            }
            if (k_old) ++tail;                         // uniform
            q ^= 1;
            __syncthreads();                           // barrier 3
        }
    }

    // ---- rebuild freelist from p; hand off per-col state for single-wave phase ----
    claim[col] = 0;
    __syncthreads();
    { const int r = p_lds[col]; if (r) claim[r] = 1; }
    __syncthreads();
    if (tid == 0) {
        int nf = 0;
        for (int r = 1; r <= N; ++r) if (!claim[r]) flist[nf++] = r;
        nfree_s = nf;
    }
    vj_lds[col] = v_j;                                 // per-col dual -> LDS
    uf[col] = (float)u_lds[col];                       // f32 mirror of row duals
    if (tid == 0) uf[0] = 0.0f;
    __syncthreads();
    const int nfree = nfree_s;

    // ==== exact Dijkstra phase: SINGLE WAVE (wave 0), 8 cols/lane, no barriers ====
    if (wid == 0) {
        // per-lane 8-column register state (ALL statically indexed via unroll)
        double xbk[8], xdk[8], vj[8];
        float  xbf[8], xdf[8], vjf[8];
        #pragma unroll
        for (int k = 0; k < 8; ++k) {
            const int c = (k << 6) + lane;             // col-1 (0-based)
            const float2 q = dgmx2[c];
            xbf[k] = q.x;          xdf[k] = q.y;
            xbk[k] = (double)q.x;  xdk[k] = (double)q.y;
            vj[k]  = vj_lds[c + 1];
            vjf[k] = (float)vj[k];
        }

        for (int kk = 0; kk < nfree; ++kk) {
            const int iroot = flist[kk];
            if (lane == 0) p_lds[0] = iroot;           // augment-walk terminator
            int    pcol[8];
            double minv[8], Dwin[8];
            float  mf[8];
            u64_t  key[8];
            unsigned usedm = 0;
            #pragma unroll
            for (int k = 0; k < 8; ++k) {
                pcol[k] = p_lds[(k << 6) + lane + 1];
                minv[k] = DBL_MAX;
                mf[k]   = (float)DBL_MAX;              // +inf: filter always passes
                Dwin[k] = 0.0;
                key[k]  = ~0ull;
            }
            double D = 0.0;
            int juse = 0, i0 = iroot;

            while (true) {
                // transition: the col that won the previous round becomes used
                #pragma unroll
                for (int k = 0; k < 8; ++k) {
                    if (((k << 6) + lane + 1) == juse) {
                        usedm |= (1u << k); Dwin[k] = D; key[k] = ~0ull;
                    }
                }
                const double2 rp  = pt[i0 - 1];        // uniform-addr broadcast
                const float2  rpf = ptf[i0 - 1];
                const double  u0  = u_lds[i0];         // static during this root
                const float   uf0 = uf[i0];
                const float   Df  = (float)D;
                #pragma unroll
                for (int k = 0; k < 8; ++k) {
                    if (!(usedm & (1u << k))) {
                        // conservative f32 filter: cand<minv <=> c<T; slack 1e-4
                        // >> total f32 err (~3e-6) => never skips a true update.
                        const float dbf = rpf.x - xbf[k], ddf = rpf.y - xdf[k];
                        const float sf  = dbf * dbf + ddf * ddf;
                        const float Tpf = ((mf[k] - Df) + uf0) + vjf[k] + 1e-4f;
                        if (Tpf > 0.0f && sf < Tpf * Tpf) {
                            const double db = rp.x - xbk[k], dd = rp.y - xdk[k];
                            const double c = sqrt(db * db + dd * dd);  // exact f64
                            const double cand = D + ((c - u0) - vj[k]);
                            if (cand < minv[k]) {
                                minv[k] = cand; mf[k] = (float)cand;
                                way_lds[(k << 6) + lane + 1] = juse;
                                key[k] = (map_f64(cand) & ~0x7FFFFull)
                                       | ((u64_t)((k << 6) + lane) << 10)
                                       | (u64_t)pcol[k];
                            }
                        }
                    }
                }
                u64_t lkey = key[0];
                #pragma unroll
                for (int k = 1; k < 8; ++k) lkey = (key[k] < lkey) ? key[k] : lkey;
                const u64_t wmin = wave_min_key(lkey);
                const unsigned whi = (unsigned)__builtin_amdgcn_readlane((int)(unsigned)(wmin >> 32), 63);
                const unsigned wlo = (unsigned)__builtin_amdgcn_readlane((int)(unsigned)wmin, 63);
                const u64_t kwin = ((u64_t)whi << 32) | wlo;
                D    = unmap_f64(kwin & ~0x7FFFFull);  // winner's (truncated) abs dist
                juse = (int)((kwin >> 10) & 511) + 1;
                i0   = (int)(kwin & 1023);             // p payload; 0 => free col
                if (i0 == 0) break;
            }

            // epilogue: settle duals (distinct rows => race-free), augment (lane 0)
            #pragma unroll
            for (int k = 0; k < 8; ++k) {
                if (usedm & (1u << k)) {
                    const double du = D - Dwin[k];     // sum of deltas while used
                    const double nu = u_lds[pcol[k]] + du;
                    u_lds[pcol[k]] = nu; uf[pcol[k]] = (float)nu;
                    vj[k] -= du; vjf[k] = (float)vj[k];
                }
            }
            if (lane == 0) {
                const double nu = u_lds[iroot] + D;    // D == D_end
                u_lds[iroot] = nu; uf[iroot] = (float)nu;
                int j = juse;
                while (j) { const int jn = way_lds[j]; p_lds[j] = p_lds[jn]; j = jn; }
            }
            // in-wave program order makes all LDS writes visible next root
        }
    }
    __syncthreads();

    // ---- loss = 0.5 * sum_j ||dgm[p[j]-1] - dgm_x[j-1]||^2 (f32 diffs like ref) ----
    const int r = p_lds[col] - 1;
    const float2 a = dgm2[r];
    const float2 b = dgmx2[tid];
    const float fb = a.x - b.x;
    const float fd = a.y - b.y;
    double acc = (double)fb * (double)fb + (double)fd * (double)fd;
    #pragma unroll
    for (int m = 32; m >= 1; m >>= 1) acc += __shfl_xor(acc, m, 64);
    if (lane == 0) red8[wid] = acc;
    __syncthreads();
    if (tid == 0) {
        double s = 0.0;
        #pragma unroll
        for (int w = 0; w < 8; ++w) s += red8[w];
        out[0] = (float)(0.5 * s);
    }
}

extern "C" void kernel_launch(void* const* d_in, const int* in_sizes, int n_in,
                              void* d_out, int out_size, void* d_ws, size_t ws_size,
                              hipStream_t stream) {
    const float* dgm   = (const float*)d_in[0];
    const float* dgm_x = (const float*)d_in[1];
    float* out = (float*)d_out;
    tofu_solver<<<1, 512, 0, stream>>>(dgm, dgm_x, out);
}

// Round 6
// 12865.089 us; speedup vs baseline: 1.0229x; 1.0229x over previous
//
#include <hip/hip_runtime.h>
#include <cfloat>
#include <math.h>

#define N 512
typedef unsigned long long u64_t;

__device__ __forceinline__ u64_t map_f64(double x) {
    u64_t b = (u64_t)__double_as_longlong(x);
    return b ^ ((b >> 63) ? 0xFFFFFFFFFFFFFFFFull : 0x8000000000000000ull);
}
__device__ __forceinline__ double unmap_f64(u64_t b) {
    b ^= ((b >> 63) ? 0x8000000000000000ull : 0xFFFFFFFFFFFFFFFFull);
    return __longlong_as_double((long long)b);
}

// wave64 u64 min-reduce via DPP (VALU pipe). Valid result in lane 63.
__device__ __forceinline__ u64_t wave_min_key(u64_t key) {
    unsigned hi = (unsigned)(key >> 32), lo = (unsigned)key;
#define MIN_STAGE(CTRL)                                                        \
    {                                                                          \
        unsigned oh = (unsigned)__builtin_amdgcn_update_dpp((int)hi, (int)hi,  \
                                                            CTRL, 0xF, 0xF, false); \
        unsigned ol = (unsigned)__builtin_amdgcn_update_dpp((int)lo, (int)lo,  \
                                                            CTRL, 0xF, 0xF, false); \
        const u64_t o = ((u64_t)oh << 32) | ol;                                \
        const u64_t c = ((u64_t)hi << 32) | lo;                                \
        if (o < c) { hi = oh; lo = ol; }                                       \
    }
    MIN_STAGE(0x111) MIN_STAGE(0x112) MIN_STAGE(0x114) MIN_STAGE(0x118)
    MIN_STAGE(0x142) MIN_STAGE(0x143)
#undef MIN_STAGE
    return ((u64_t)hi << 32) | lo;
}

// ws layout (f64-first for alignment):
//  u_ws   = ws[0 .. 512]        row duals
//  vj_ws  = ws[513 .. 1025]     col duals (index by col)
//  p_ws   = (int*)(ws+1026)[0 .. 512]
//  fl_ws  = p_ws + 513          [0 .. 511]
//  nf_ws  = fl_ws + 512

// ==== K1: 512 thr / 8 waves — column reduction + greedy + ARR (R4-identical) ====
__global__ __launch_bounds__(512, 1) void tofu_stage1(
    const float* __restrict__ dgm, const float* __restrict__ dgm_x,
    double* __restrict__ ws)
{
#pragma clang fp contract(off)
    __shared__ double2 pt[N];
    __shared__ double  u_lds[N + 1];
    __shared__ int     p_lds[N + 1];
    __shared__ int     claim[N + 1];
    __shared__ int     flist[4 * N + 32];
    __shared__ u64_t   aslot[2], bslot[2];
    __shared__ double  v1x;
    __shared__ int     nfree_s;

    const int tid  = threadIdx.x;       // 0..511
    const int col  = tid + 1;           // 1..512
    const int lane = tid & 63;
    const float2* dgm2  = (const float2*)dgm;
    const float2* dgmx2 = (const float2*)dgm_x;

    {
        const float2 p2 = dgm2[tid];
        pt[tid] = make_double2((double)p2.x, (double)p2.y);
    }
    const float2 q2 = dgmx2[tid];
    const double xb = (double)q2.x, xd = (double)q2.y;
    u_lds[col] = 0.0; p_lds[col] = 0; claim[col] = 0x7fffffff;
    if (tid == 0) {
        u_lds[0] = 0.0; p_lds[0] = 0; claim[0] = 0x7fffffff;
        aslot[0] = aslot[1] = ~0ull; bslot[0] = bslot[1] = ~0ull;
    }
    __syncthreads();

    // ---- column reduction: argmin over squared dist (sqrt monotone => same v) ----
    double v_j; int amin;
    {
        double vsq = DBL_MAX; amin = 1;
        for (int i = 0; i < N; ++i) {
            const double2 rp = pt[i];
            const double db = rp.x - xb, dd = rp.y - xd;
            const double sq = db * db + dd * dd;
            if (sq < vsq) { vsq = sq; amin = i + 1; }
        }
        v_j = sqrt(vsq);
    }

    // ---- greedy tight matching ----
    atomicMin(&claim[amin], col);
    __syncthreads();
    if (claim[amin] == col) p_lds[col] = amin;
    __syncthreads();
    claim[col] = 0;
    __syncthreads();
    { const int r = p_lds[col]; if (r) claim[r] = 1; }
    __syncthreads();
    if (tid == 0) {
        int nf = 0;
        for (int r = 1; r <= N; ++r) if (!claim[r]) flist[nf++] = r;
        nfree_s = nf;
    }
    __syncthreads();

    // ---- LAPJV augmenting row reduction (exactness-preserving, capped) ----
    {
        int head = 0, tail = nfree_s, q = 0;
        const int cap = 3 * tail + 16;
        int myp = p_lds[col];
        for (int step = 0; step < cap && head < tail; ++step) {
            const int i = flist[head++];
            const double2 rp = pt[i - 1];
            const double db = rp.x - xb, dd = rp.y - xd;
            const double val = sqrt(db * db + dd * dd) - v_j;
            const u64_t key = (map_f64(val) & ~0x7FFFFull)
                            | ((u64_t)(col - 1) << 10) | (u64_t)myp;
            u64_t kr = wave_min_key(key);
            if (lane == 63) atomicMin(&aslot[q], kr);
            __syncthreads();                           // barrier 1
            const u64_t k1 = aslot[q];
            const int j1    = (int)((k1 >> 10) & 511) + 1;
            const int k_old = (int)(k1 & 1023);
            if (col == j1) v1x = val;
            kr = wave_min_key((col == j1) ? ~0ull : key);
            if (lane == 63) atomicMin(&bslot[q], kr);
            __syncthreads();                           // barrier 2
            const double m2t = unmap_f64(bslot[q] & ~0x7FFFFull);
            const double v1e = v1x;
            const double ui  = fmax(m2t, v1e);
            if (col == j1) { v_j -= (ui - val); myp = i; }
            if (tid == 0) {
                u_lds[i] = ui;
                p_lds[j1] = i;
                if (k_old) flist[tail] = k_old;
                aslot[q ^ 1] = ~0ull; bslot[q ^ 1] = ~0ull;
            }
            if (k_old) ++tail;
            q ^= 1;
            __syncthreads();                           // barrier 3
        }
    }

    // ---- rebuild freelist, dump state to ws ----
    claim[col] = 0;
    __syncthreads();
    { const int r = p_lds[col]; if (r) claim[r] = 1; }
    __syncthreads();
    if (tid == 0) {
        int nf = 0;
        for (int r = 1; r <= N; ++r) if (!claim[r]) flist[nf++] = r;
        nfree_s = nf;
    }
    __syncthreads();
    const int nfree = nfree_s;

    double* u_ws  = ws;
    double* vj_ws = ws + 513;
    int*    p_ws  = (int*)(ws + 1026);
    int*    fl_ws = p_ws + 513;
    int*    nf_ws = fl_ws + 512;
    u_ws[col]  = u_lds[col];
    vj_ws[col] = v_j;
    p_ws[col]  = p_lds[col];
    fl_ws[tid] = (tid < nfree) ? flist[tid] : 0;
    if (tid == 0) { u_ws[0] = 0.0; vj_ws[0] = 0.0; p_ws[0] = 0; nf_ws[0] = nfree; }
}

// ==== K2: 64 thr / ONE wave — barrier-free exact Dijkstra (R5-validated path) ====
// 8 cols/lane, all per-col state in registers (statically indexed); 64-thread
// launch gives the allocator the full 256-VGPR budget (R5's 512-thr launch
// capped at 128 and spilled to scratch => 2950cy/iter; modeled no-spill ~550).
__global__ __launch_bounds__(64, 1) void tofu_stage2(
    const float* __restrict__ dgm, const float* __restrict__ dgm_x,
    double* __restrict__ ws)
{
#pragma clang fp contract(off)
    __shared__ double2 pt[N];
    __shared__ float2  ptf[N];
    __shared__ double  u_lds[N + 1];
    __shared__ float   uf[N + 1];
    __shared__ int     p_lds[N + 1];
    __shared__ int     way_lds[N + 1];
    __shared__ int     flist[N];

    const int lane = threadIdx.x;       // 0..63 (single wave)
    const float2* dgm2  = (const float2*)dgm;
    const float2* dgmx2 = (const float2*)dgm_x;
    double* u_ws  = ws;
    double* vj_ws = ws + 513;
    int*    p_ws  = (int*)(ws + 1026);
    int*    fl_ws = p_ws + 513;
    int*    nf_ws = fl_ws + 512;

    // ---- stage state: LDS mirrors + per-lane 8-column register state ----
    double xbk[8], xdk[8], vj[8];
    float  xbf[8], xdf[8], vjf[8];
    #pragma unroll
    for (int k = 0; k < 8; ++k) {
        const int c = (k << 6) + lane;             // col-1 (0-based)
        const float2 p2 = dgm2[c];
        pt[c]  = make_double2((double)p2.x, (double)p2.y);
        ptf[c] = p2;
        const float2 q = dgmx2[c];
        xbf[k] = q.x;          xdf[k] = q.y;
        xbk[k] = (double)q.x;  xdk[k] = (double)q.y;
        vj[k]  = vj_ws[c + 1];
        vjf[k] = (float)vj[k];
        const double uu = u_ws[c + 1];
        u_lds[c + 1] = uu; uf[c + 1] = (float)uu;
        p_lds[c + 1] = p_ws[c + 1];
        way_lds[c + 1] = 0;
        flist[c] = fl_ws[c];
    }
    if (lane == 0) {
        u_lds[0] = 0.0; uf[0] = 0.0f; p_lds[0] = 0; way_lds[0] = 0;
    }
    const int nfree = nf_ws[0];                    // uniform broadcast load
    __threadfence_block();                         // order LDS writes before reads

    for (int kk = 0; kk < nfree; ++kk) {
        const int iroot = flist[kk];
        if (lane == 0) p_lds[0] = iroot;           // augment-walk terminator
        int    pcol[8];
        double minv[8], Dwin[8];
        float  mf[8];
        u64_t  key[8];
        unsigned usedm = 0;
        #pragma unroll
        for (int k = 0; k < 8; ++k) {
            pcol[k] = p_lds[(k << 6) + lane + 1];
            minv[k] = DBL_MAX;
            mf[k]   = (float)DBL_MAX;              // +inf: filter always passes
            Dwin[k] = 0.0;
            key[k]  = ~0ull;
        }
        double D = 0.0;
        int juse = 0, i0 = iroot;

        while (true) {
            // transition: the col that won the previous round becomes used
            #pragma unroll
            for (int k = 0; k < 8; ++k) {
                if (((k << 6) + lane + 1) == juse) {
                    usedm |= (1u << k); Dwin[k] = D; key[k] = ~0ull;
                }
            }
            const double2 rp  = pt[i0 - 1];        // uniform-addr broadcast
            const float2  rpf = ptf[i0 - 1];
            const double  u0  = u_lds[i0];         // static during this root
            const float   uf0 = uf[i0];
            const float   Df  = (float)D;
            #pragma unroll
            for (int k = 0; k < 8; ++k) {
                if (!(usedm & (1u << k))) {
                    // conservative f32 filter: cand<minv <=> c<T; slack 1e-4
                    // >> total f32 err (~3e-6) => never skips a true update.
                    const float dbf = rpf.x - xbf[k], ddf = rpf.y - xdf[k];
                    const float sf  = dbf * dbf + ddf * ddf;
                    const float Tpf = ((mf[k] - Df) + uf0) + vjf[k] + 1e-4f;
                    if (Tpf > 0.0f && sf < Tpf * Tpf) {
                        const double db = rp.x - xbk[k], dd = rp.y - xdk[k];
                        const double c = sqrt(db * db + dd * dd);  // exact f64
                        const double cand = D + ((c - u0) - vj[k]);
                        if (cand < minv[k]) {
                            minv[k] = cand; mf[k] = (float)cand;
                            way_lds[(k << 6) + lane + 1] = juse;
                            key[k] = (map_f64(cand) & ~0x7FFFFull)
                                   | ((u64_t)((k << 6) + lane) << 10)
                                   | (u64_t)pcol[k];
                        }
                    }
                }
            }
            u64_t lkey = key[0];
            #pragma unroll
            for (int k = 1; k < 8; ++k) lkey = (key[k] < lkey) ? key[k] : lkey;
            const u64_t wmin = wave_min_key(lkey);
            const unsigned whi = (unsigned)__builtin_amdgcn_readlane((int)(unsigned)(wmin >> 32), 63);
            const unsigned wlo = (unsigned)__builtin_amdgcn_readlane((int)(unsigned)wmin, 63);
            const u64_t kwin = ((u64_t)whi << 32) | wlo;
            D    = unmap_f64(kwin & ~0x7FFFFull);  // winner's (truncated) abs dist
            juse = (int)((kwin >> 10) & 511) + 1;
            i0   = (int)(kwin & 1023);             // p payload; 0 => free col
            if (i0 == 0) break;
        }

        // epilogue: settle duals (distinct rows => race-free), augment (lane 0)
        #pragma unroll
        for (int k = 0; k < 8; ++k) {
            if (usedm & (1u << k)) {
                const double du = D - Dwin[k];     // sum of deltas while used
                const double nu = u_lds[pcol[k]] + du;
                u_lds[pcol[k]] = nu; uf[pcol[k]] = (float)nu;
                vj[k] -= du; vjf[k] = (float)vj[k];
            }
        }
        if (lane == 0) {
            const double nu = u_lds[iroot] + D;    // D == D_end
            u_lds[iroot] = nu; uf[iroot] = (float)nu;
            int j = juse;
            while (j) { const int jn = way_lds[j]; p_lds[j] = p_lds[jn]; j = jn; }
        }
        // in-wave DS program order makes all LDS writes visible next root
    }

    // ---- write final assignment back ----
    __threadfence_block();
    #pragma unroll
    for (int k = 0; k < 8; ++k) {
        const int c = (k << 6) + lane;
        p_ws[c + 1] = p_lds[c + 1];
    }
}

// ==== K3: 512 thr — loss, summation order bit-identical to R4 ====
__global__ __launch_bounds__(512, 1) void tofu_loss(
    const float* __restrict__ dgm, const float* __restrict__ dgm_x,
    const double* __restrict__ ws, float* __restrict__ out)
{
#pragma clang fp contract(off)
    __shared__ double red8[8];
    const int tid  = threadIdx.x;
    const int lane = tid & 63;
    const int wid  = tid >> 6;
    const float2* dgm2  = (const float2*)dgm;
    const float2* dgmx2 = (const float2*)dgm_x;
    const int* p_ws = (const int*)(ws + 1026);

    const int r = p_ws[tid + 1] - 1;
    const float2 a = dgm2[r];
    const float2 b = dgmx2[tid];
    const float fb = a.x - b.x;
    const float fd = a.y - b.y;
    double acc = (double)fb * (double)fb + (double)fd * (double)fd;
    #pragma unroll
    for (int m = 32; m >= 1; m >>= 1) acc += __shfl_xor(acc, m, 64);
    if (lane == 0) red8[wid] = acc;
    __syncthreads();
    if (tid == 0) {
        double s = 0.0;
        #pragma unroll
        for (int w = 0; w < 8; ++w) s += red8[w];
        out[0] = (float)(0.5 * s);
    }
}

extern "C" void kernel_launch(void* const* d_in, const int* in_sizes, int n_in,
                              void* d_out, int out_size, void* d_ws, size_t ws_size,
                              hipStream_t stream) {
    const float* dgm   = (const float*)d_in[0];
    const float* dgm_x = (const float*)d_in[1];
    float* out = (float*)d_out;
    double* ws = (double*)d_ws;
    tofu_stage1<<<1, 512, 0, stream>>>(dgm, dgm_x, ws);
    tofu_stage2<<<1, 64, 0, stream>>>(dgm, dgm_x, ws);
    tofu_loss<<<1, 512, 0, stream>>>(dgm, dgm_x, ws, out);
}

// Round 7
// 6249.017 us; speedup vs baseline: 2.1060x; 2.0587x over previous
//
#include <hip/hip_runtime.h>
#include <cfloat>
#include <math.h>

#define N 512
typedef unsigned long long u64_t;

__device__ __forceinline__ u64_t map_f64(double x) {
    u64_t b = (u64_t)__double_as_longlong(x);
    return b ^ ((b >> 63) ? 0xFFFFFFFFFFFFFFFFull : 0x8000000000000000ull);
}
__device__ __forceinline__ double unmap_f64(u64_t b) {
    b ^= ((b >> 63) ? 0x8000000000000000ull : 0xFFFFFFFFFFFFFFFFull);
    return __longlong_as_double((long long)b);
}

// wave64 u64 min-reduce via DPP (VALU pipe). Valid result in lane 63.
// row_shr:1/2/4/8 reduce within 16-lane rows; row_bcast:15/31 merge rows.
// bound_ctrl=false + old=own value => lanes w/o source keep own (min identity).
__device__ __forceinline__ u64_t wave_min_key(u64_t key) {
    unsigned hi = (unsigned)(key >> 32), lo = (unsigned)key;
#define MIN_STAGE(CTRL)                                                        \
    {                                                                          \
        unsigned oh = (unsigned)__builtin_amdgcn_update_dpp((int)hi, (int)hi,  \
                                                            CTRL, 0xF, 0xF, false); \
        unsigned ol = (unsigned)__builtin_amdgcn_update_dpp((int)lo, (int)lo,  \
                                                            CTRL, 0xF, 0xF, false); \
        const u64_t o = ((u64_t)oh << 32) | ol;                                \
        const u64_t c = ((u64_t)hi << 32) | lo;                                \
        if (o < c) { hi = oh; lo = ol; }                                       \
    }
    MIN_STAGE(0x111) MIN_STAGE(0x112) MIN_STAGE(0x114) MIN_STAGE(0x118)
    MIN_STAGE(0x142) MIN_STAGE(0x143)
#undef MIN_STAGE
    return ((u64_t)hi << 32) | lo;
}

// 512 threads / 8 waves, thread t owns column t+1. Exact JV:
// column reduction + greedy tight match + LAPJV ARR warm start, then
// Dijkstra with DPP wave-reduce + 8-way atomicMin combine.
// key = [45b value | 9b col-1 | 10b p[col]] (truncation precedent: absmax 0).
// Ledger: R1 L2-cost-matrix worse (+100cy/iter latency); R2 2nd ARR pass churns
// (+715us); R3 4-wave/2-col worse; R5/R6 single-wave Dijkstra 3100cy/iter
// (latency fully exposed) — 8-wave barrier structure is the best latency-hider.
// R4 (this base): absolute labels + sqrt filter + wave-min cache = 5643us.
// R7 delta: f32 filter (R5/R6-validated: slack 1e-4 >> f32 err ~4e-7; passing
// lanes re-test in exact f64 => updates bit-identical) to cut f64 issue
// pressure (f64 ops are 4cy/wave64 issue slots, contended at 2 waves/SIMD),
// + strength-reduced mod-3 rotation. f64 pt/u loads stay unconditional so the
// winner's sqrt chain doesn't grow a dependent load.
__global__ __launch_bounds__(512, 1) void tofu_solver(
    const float* __restrict__ dgm, const float* __restrict__ dgm_x,
    float* __restrict__ out)
{
#pragma clang fp contract(off)
    __shared__ double2 pt[N];
    __shared__ float2  ptf[N];
    __shared__ double  u_lds[N + 1];
    __shared__ float   uf[N + 1];
    __shared__ int     p_lds[N + 1];
    __shared__ int     way_lds[N + 1];
    __shared__ int     claim[N + 1];
    __shared__ int     flist[4 * N + 32];
    __shared__ u64_t   dslot[3];        // Dijkstra combine slots (mod-3 rotation)
    __shared__ u64_t   aslot[2], bslot[2];  // ARR slots (parity)
    __shared__ double  v1x;
    __shared__ double  red8[8];
    __shared__ int     nfree_s;

    const int tid  = threadIdx.x;       // 0..511
    const int col  = tid + 1;           // 1..512
    const int lane = tid & 63;
    const int wid  = tid >> 6;
    const float2* dgm2  = (const float2*)dgm;
    const float2* dgmx2 = (const float2*)dgm_x;

    // ---- stage points; own column's target point in registers ----
    {
        const float2 p2 = dgm2[tid];
        pt[tid]  = make_double2((double)p2.x, (double)p2.y);
        ptf[tid] = p2;
    }
    const float2 q2 = dgmx2[tid];
    const double xb  = (double)q2.x, xd  = (double)q2.y;
    const float  xbf = q2.x,         xdf = q2.y;
    u_lds[col] = 0.0; p_lds[col] = 0; way_lds[col] = 0; claim[col] = 0x7fffffff;
    if (tid == 0) {
        u_lds[0] = 0.0; p_lds[0] = 0; way_lds[0] = 0; claim[0] = 0x7fffffff;
        dslot[0] = dslot[1] = dslot[2] = ~0ull;
        aslot[0] = aslot[1] = ~0ull; bslot[0] = bslot[1] = ~0ull;
    }
    __syncthreads();

    // ---- column reduction: argmin over squared dist (sqrt monotone => same v) ----
    double v_j; int amin;
    {
        double vsq = DBL_MAX; amin = 1;
        for (int i = 0; i < N; ++i) {
            const double2 rp = pt[i];                 // broadcast b128
            const double db = rp.x - xb, dd = rp.y - xd;
            const double sq = db * db + dd * dd;
            if (sq < vsq) { vsq = sq; amin = i + 1; }
        }
        v_j = sqrt(vsq);                              // exact: sqrt(min) == min(sqrt)
    }

    // ---- greedy tight matching: row r -> smallest col whose argmin is r ----
    atomicMin(&claim[amin], col);
    __syncthreads();
    if (claim[amin] == col) p_lds[col] = amin;        // tight: c=v[col], u=0
    __syncthreads();
    // freelist of unmatched rows
    claim[col] = 0;
    __syncthreads();
    { const int r = p_lds[col]; if (r) claim[r] = 1; }
    __syncthreads();
    if (tid == 0) {
        int nf = 0;
        for (int r = 1; r <= N; ++r) if (!claim[r]) flist[nf++] = r;
        nfree_s = nf;
    }
    __syncthreads();

    // ---- LAPJV augmenting row reduction (exactness-preserving, capped) ----
    {
        int head = 0, tail = nfree_s, q = 0;
        const int cap = 3 * tail + 16;
        int myp = p_lds[col];                          // register copy of p[col]
        for (int step = 0; step < cap && head < tail; ++step) {
            const int i = flist[head++];               // uniform broadcast
            const double2 rp = pt[i - 1];
            const double db = rp.x - xb, dd = rp.y - xd;
            const double val = sqrt(db * db + dd * dd) - v_j;   // exact f64
            const u64_t key = (map_f64(val) & ~0x7FFFFull)
                            | ((u64_t)(col - 1) << 10) | (u64_t)myp;
            u64_t kr = wave_min_key(key);
            if (lane == 63) atomicMin(&aslot[q], kr);
            __syncthreads();                           // barrier 1
            const u64_t k1 = aslot[q];
            const int j1    = (int)((k1 >> 10) & 511) + 1;
            const int k_old = (int)(k1 & 1023);
            if (col == j1) v1x = val;                  // exact v1 handoff
            kr = wave_min_key((col == j1) ? ~0ull : key);
            if (lane == 63) atomicMin(&bslot[q], kr);
            __syncthreads();                           // barrier 2
            const double m2t = unmap_f64(bslot[q] & ~0x7FFFFull);  // <= true 2nd-min
            const double v1e = v1x;
            const double ui  = fmax(m2t, v1e);         // feasible AND tight on j1
            if (col == j1) { v_j -= (ui - val); myp = i; }
            if (tid == 0) {
                u_lds[i] = ui;
                p_lds[j1] = i;
                if (k_old) flist[tail] = k_old;
                aslot[q ^ 1] = ~0ull; bslot[q ^ 1] = ~0ull;  // safe: 2 barriers since last read
            }
            if (k_old) ++tail;                         // uniform
            q ^= 1;
            __syncthreads();                           // barrier 3
        }
    }

    // ---- rebuild freelist from p; build f32 dual mirror ----
    claim[col] = 0;
    __syncthreads();
    { const int r = p_lds[col]; if (r) claim[r] = 1; }
    __syncthreads();
    if (tid == 0) {
        int nf = 0;
        for (int r = 1; r <= N; ++r) if (!claim[r]) flist[nf++] = r;
        nfree_s = nf;
    }
    uf[col] = (float)u_lds[col];                       // f32 mirror of row duals
    if (tid == 0) uf[0] = 0.0f;
    __syncthreads();
    const int nfree = nfree_s;
    float vjf = (float)v_j;                            // f32 mirror of own col dual

    // ---- exact Dijkstra phase (absolute labels + f32 filter + wave-min cache) ----
    for (int kk = 0; kk < nfree; ++kk) {
        const int iroot = flist[kk];                   // ordered by prev end barrier
        const int pcol  = p_lds[col];                  // static during this Dijkstra
        if (tid == 0) p_lds[0] = iroot;                // only tid0 reads p[0] (augment)
        double minv = DBL_MAX;                         // ABSOLUTE dist label (stable)
        float  mf   = (float)DBL_MAX;                  // == +inf: filter always passes
        double D = 0.0, Dwin = 0.0;                    // uniform frontier dist / win dist
        bool used = false;
        int juse = 0, i0 = iroot, par = 0;
        u64_t key  = ~0ull;                            // cached own key
        u64_t wmin = ~0ull;                            // lane63's cached wave-min

        while (true) {
            // ---- A-phase ----
            bool trans = false;
            if (col == juse) {                         // prev winner: mark used
                used = true; Dwin = D; trans = true; key = ~0ull;
            }
            const double2 rp  = pt[i0 - 1];            // broadcast b128 (uncond: keeps
            const float2  rpf = ptf[i0 - 1];           //  sqrt chain load-free)
            const double  u0  = u_lds[i0];             // untouched this Dijkstra
            const float   uf0 = uf[i0];
            bool upd = false;
            if (!used) {
                // conservative f32 filter (R5/R6-validated): cand<minv <=> c<T;
                // slack 1e-4 >> total f32 err (~4e-7) => never skips a true update.
                const float dbf = rpf.x - xbf, ddf = rpf.y - xdf;
                const float sf  = dbf * dbf + ddf * ddf;
                const float Tpf = ((mf - (float)D) + uf0) + vjf + 1e-4f;
                if (Tpf > 0.0f && sf < Tpf * Tpf) {
                    const double db = rp.x - xb, dd = rp.y - xd;
                    const double c = sqrt(db * db + dd * dd);   // exact f64
                    const double cand = D + ((c - u0) - v_j);
                    if (cand < minv) {
                        minv = cand; mf = (float)cand;
                        way_lds[col] = juse; upd = true;
                        key = (map_f64(cand) & ~0x7FFFFull)
                            | ((u64_t)(col - 1) << 10) | (u64_t)pcol;
                    }
                }
            }
            if (__any((int)(upd || trans))) {          // wave-uniform: keys changed?
                wmin = wave_min_key(key);
            }
            if (lane == 63) atomicMin(&dslot[par], wmin);
            __syncthreads();
            // ---- B-phase ----
            const u64_t k = dslot[par];
            if (tid == 0) dslot[par == 0 ? 2 : par - 1] = ~0ull;  // 2 barriers since read
            D = unmap_f64(k & ~0x7FFFFull);            // winner's (truncated) abs dist
            juse = (int)((k >> 10) & 511) + 1;
            i0   = (int)(k & 1023);                    // p payload; 0 => free col
            if (i0 == 0) break;
            par = (par == 2) ? 0 : par + 1;
        }

        // epilogue: settle duals (distinct rows => race-free), augment, clean slot
        if (used) {
            const double du = D - Dwin;                // == sum of deltas while used
            const double nu = u_lds[pcol] + du;
            u_lds[pcol] = nu; uf[pcol] = (float)nu;
            v_j -= du; vjf = (float)v_j;
        }
        if (tid == 0) {
            const double nu = u_lds[iroot] + D;        // D == D_end
            u_lds[iroot] = nu; uf[iroot] = (float)nu;
            dslot[par] = ~0ull;                        // the slot just consumed
            int j = juse;
            while (j) { const int jn = way_lds[j]; p_lds[j] = p_lds[jn]; j = jn; }
        }
        __syncthreads();
    }

    // ---- loss = 0.5 * sum_j ||dgm[p[j]-1] - dgm_x[j-1]||^2 (f32 diffs like ref) ----
    const int r = p_lds[col] - 1;
    const float2 a = dgm2[r];
    const float2 b = dgmx2[tid];
    const float fb = a.x - b.x;
    const float fd = a.y - b.y;
    double acc = (double)fb * (double)fb + (double)fd * (double)fd;
    #pragma unroll
    for (int m = 32; m >= 1; m >>= 1) acc += __shfl_xor(acc, m, 64);
    if (lane == 0) red8[wid] = acc;
    __syncthreads();
    if (tid == 0) {
        double s = 0.0;
        #pragma unroll
        for (int w = 0; w < 8; ++w) s += red8[w];
        out[0] = (float)(0.5 * s);
    }
}

extern "C" void kernel_launch(void* const* d_in, const int* in_sizes, int n_in,
                              void* d_out, int out_size, void* d_ws, size_t ws_size,
                              hipStream_t stream) {
    const float* dgm   = (const float*)d_in[0];
    const float* dgm_x = (const float*)d_in[1];
    float* out = (float*)d_out;
    tofu_solver<<<1, 512, 0, stream>>>(dgm, dgm_x, out);
}

// Round 8
// 5641.284 us; speedup vs baseline: 2.3328x; 1.1077x over previous
//
#include <hip/hip_runtime.h>
#include <cfloat>
#include <math.h>

#define N 512
typedef unsigned long long u64_t;

__device__ __forceinline__ u64_t map_f64(double x) {
    u64_t b = (u64_t)__double_as_longlong(x);
    return b ^ ((b >> 63) ? 0xFFFFFFFFFFFFFFFFull : 0x8000000000000000ull);
}
__device__ __forceinline__ double unmap_f64(u64_t b) {
    b ^= ((b >> 63) ? 0x8000000000000000ull : 0xFFFFFFFFFFFFFFFFull);
    return __longlong_as_double((long long)b);
}

// wave64 u64 min-reduce via DPP (VALU pipe). Valid result in lane 63.
// row_shr:1/2/4/8 reduce within 16-lane rows; row_bcast:15/31 merge rows.
// bound_ctrl=false + old=own value => lanes w/o source keep own (min identity).
__device__ __forceinline__ u64_t wave_min_key(u64_t key) {
    unsigned hi = (unsigned)(key >> 32), lo = (unsigned)key;
#define MIN_STAGE(CTRL)                                                        \
    {                                                                          \
        unsigned oh = (unsigned)__builtin_amdgcn_update_dpp((int)hi, (int)hi,  \
                                                            CTRL, 0xF, 0xF, false); \
        unsigned ol = (unsigned)__builtin_amdgcn_update_dpp((int)lo, (int)lo,  \
                                                            CTRL, 0xF, 0xF, false); \
        const u64_t o = ((u64_t)oh << 32) | ol;                                \
        const u64_t c = ((u64_t)hi << 32) | lo;                                \
        if (o < c) { hi = oh; lo = ol; }                                       \
    }
    MIN_STAGE(0x111) MIN_STAGE(0x112) MIN_STAGE(0x114) MIN_STAGE(0x118)
    MIN_STAGE(0x142) MIN_STAGE(0x143)
#undef MIN_STAGE
    return ((u64_t)hi << 32) | lo;
}

// 512 threads / 8 waves, thread t owns column t+1. Exact JV:
// column reduction + greedy tight match + LAPJV ARR warm start, then
// Dijkstra with DPP wave-reduce + 8-way atomicMin combine.
// key = [45b value | 9b col-1 | 10b p[col]] (truncation precedent: absmax 0).
// CONVERGED (R0-R7 ledger): per-iteration interval ~1050cy = LDS round-trips
// + barrier + DPP; VALU work is off the critical path. Falsified alternatives:
//  R1 L2 cost matrix (+100cy/iter latency), R2 2nd ARR pass (churn, +715us),
//  R3 4-wave/2-col no-atomic (worse), R5/R6 single-wave barrier-free Dijkstra
//  (3100cy/iter; latency fully exposed — 8-wave barrier structure is the best
//  latency-hider), R7 f32 filter via LDS mirrors (+2 LDS reads on critical
//  path, worse). This R4 config: absolute labels + register-only f64 sqrt
//  filter + wave-min caching = best verified (5643us, absmax 0).
__global__ __launch_bounds__(512, 1) void tofu_solver(
    const float* __restrict__ dgm, const float* __restrict__ dgm_x,
    float* __restrict__ out)
{
#pragma clang fp contract(off)
    __shared__ double2 pt[N];
    __shared__ double  u_lds[N + 1];
    __shared__ int     p_lds[N + 1];
    __shared__ int     way_lds[N + 1];
    __shared__ int     claim[N + 1];
    __shared__ int     flist[4 * N + 32];
    __shared__ u64_t   dslot[3];        // Dijkstra combine slots (mod-3 rotation)
    __shared__ u64_t   aslot[2], bslot[2];  // ARR slots (parity)
    __shared__ double  v1x;
    __shared__ double  red8[8];
    __shared__ int     nfree_s;

    const int tid  = threadIdx.x;       // 0..511
    const int col  = tid + 1;           // 1..512
    const int lane = tid & 63;
    const int wid  = tid >> 6;
    const float2* dgm2  = (const float2*)dgm;
    const float2* dgmx2 = (const float2*)dgm_x;

    // ---- stage points; own column's target point in registers ----
    {
        const float2 p2 = dgm2[tid];
        pt[tid] = make_double2((double)p2.x, (double)p2.y);
    }
    const float2 q2 = dgmx2[tid];
    const double xb = (double)q2.x, xd = (double)q2.y;
    u_lds[col] = 0.0; p_lds[col] = 0; way_lds[col] = 0; claim[col] = 0x7fffffff;
    if (tid == 0) {
        u_lds[0] = 0.0; p_lds[0] = 0; way_lds[0] = 0; claim[0] = 0x7fffffff;
        dslot[0] = dslot[1] = dslot[2] = ~0ull;
        aslot[0] = aslot[1] = ~0ull; bslot[0] = bslot[1] = ~0ull;
    }
    __syncthreads();

    // ---- column reduction: argmin over squared dist (sqrt monotone => same v) ----
    double v_j; int amin;
    {
        double vsq = DBL_MAX; amin = 1;
        for (int i = 0; i < N; ++i) {
            const double2 rp = pt[i];                 // broadcast b128
            const double db = rp.x - xb, dd = rp.y - xd;
            const double sq = db * db + dd * dd;
            if (sq < vsq) { vsq = sq; amin = i + 1; }
        }
        v_j = sqrt(vsq);                              // exact: sqrt(min) == min(sqrt)
    }

    // ---- greedy tight matching: row r -> smallest col whose argmin is r ----
    atomicMin(&claim[amin], col);
    __syncthreads();
    if (claim[amin] == col) p_lds[col] = amin;        // tight: c=v[col], u=0
    __syncthreads();
    // freelist of unmatched rows
    claim[col] = 0;
    __syncthreads();
    { const int r = p_lds[col]; if (r) claim[r] = 1; }
    __syncthreads();
    if (tid == 0) {
        int nf = 0;
        for (int r = 1; r <= N; ++r) if (!claim[r]) flist[nf++] = r;
        nfree_s = nf;
    }
    __syncthreads();

    // ---- LAPJV augmenting row reduction (exactness-preserving, capped) ----
    {
        int head = 0, tail = nfree_s, q = 0;
        const int cap = 3 * tail + 16;
        int myp = p_lds[col];                          // register copy of p[col]
        for (int step = 0; step < cap && head < tail; ++step) {
            const int i = flist[head++];               // uniform broadcast
            const double2 rp = pt[i - 1];
            const double db = rp.x - xb, dd = rp.y - xd;
            const double val = sqrt(db * db + dd * dd) - v_j;   // exact f64
            const u64_t key = (map_f64(val) & ~0x7FFFFull)
                            | ((u64_t)(col - 1) << 10) | (u64_t)myp;
            u64_t kr = wave_min_key(key);
            if (lane == 63) atomicMin(&aslot[q], kr);
            __syncthreads();                           // barrier 1
            const u64_t k1 = aslot[q];
            const int j1    = (int)((k1 >> 10) & 511) + 1;
            const int k_old = (int)(k1 & 1023);
            if (col == j1) v1x = val;                  // exact v1 handoff
            kr = wave_min_key((col == j1) ? ~0ull : key);
            if (lane == 63) atomicMin(&bslot[q], kr);
            __syncthreads();                           // barrier 2
            const double m2t = unmap_f64(bslot[q] & ~0x7FFFFull);  // <= true 2nd-min
            const double v1e = v1x;
            const double ui  = fmax(m2t, v1e);         // feasible AND tight on j1
            if (col == j1) { v_j -= (ui - val); myp = i; }
            if (tid == 0) {
                u_lds[i] = ui;
                p_lds[j1] = i;
                if (k_old) flist[tail] = k_old;
                aslot[q ^ 1] = ~0ull; bslot[q ^ 1] = ~0ull;  // safe: 2 barriers since last read
            }
            if (k_old) ++tail;                         // uniform
            q ^= 1;
            __syncthreads();                           // barrier 3
        }
    }

    // ---- rebuild freelist from p ----
    claim[col] = 0;
    __syncthreads();
    { const int r = p_lds[col]; if (r) claim[r] = 1; }
    __syncthreads();
    if (tid == 0) {
        int nf = 0;
        for (int r = 1; r <= N; ++r) if (!claim[r]) flist[nf++] = r;
        nfree_s = nf;
    }
    __syncthreads();
    const int nfree = nfree_s;

    // ---- exact Dijkstra phase (absolute labels + sqrt filter + wave-min cache) ----
    for (int kk = 0; kk < nfree; ++kk) {
        const int iroot = flist[kk];                   // ordered by prev end barrier
        const int pcol  = p_lds[col];                  // static during this Dijkstra
        if (tid == 0) p_lds[0] = iroot;                // only tid0 reads p[0] (augment)
        double minv = DBL_MAX;                         // ABSOLUTE dist label (stable)
        double D = 0.0, Dwin = 0.0;                    // uniform frontier dist / win dist
        bool used = false;
        int juse = 0, i0 = iroot, par = 0;
        u64_t key  = ~0ull;                            // cached own key
        u64_t wmin = ~0ull;                            // lane63's cached wave-min

        while (true) {
            // ---- A-phase ----
            bool trans = false;
            if (col == juse) {                         // prev winner: mark used
                used = true; Dwin = D; trans = true; key = ~0ull;
            }
            const double2 rp = pt[i0 - 1];             // broadcast b128
            const double u0 = u_lds[i0];               // untouched this Dijkstra
            bool upd = false;
            if (!used) {
                const double db = rp.x - xb, dd = rp.y - xd;
                const double s = db * db + dd * dd;
                // cand < minv  <=>  c < ((minv - D) + u0) + v_j  (exact algebra);
                // conservative filter with 1e-12 abs slack (>> fl error) so only
                // provably-no-update lanes skip the sqrt.
                const double T  = ((minv - D) + u0) + v_j;
                const double Tp = T + 1e-12;
                if (Tp > 0.0 && s < Tp * Tp) {
                    const double c = sqrt(s);          // exact f64, same expr as before
                    const double cand = D + ((c - u0) - v_j);
                    if (cand < minv) {
                        minv = cand; way_lds[col] = juse; upd = true;
                        key = (map_f64(minv) & ~0x7FFFFull)
                            | ((u64_t)(col - 1) << 10) | (u64_t)pcol;
                    }
                }
            }
            if (__any((int)(upd || trans))) {          // wave-uniform: keys changed?
                wmin = wave_min_key(key);
            }
            if (lane == 63) atomicMin(&dslot[par], wmin);
            __syncthreads();
            // ---- B-phase ----
            const u64_t k = dslot[par];
            if (tid == 0) dslot[(par + 2) % 3] = ~0ull;  // last read 2 barriers ago
            D = unmap_f64(k & ~0x7FFFFull);            // winner's (truncated) abs dist
            juse = (int)((k >> 10) & 511) + 1;
            i0   = (int)(k & 1023);                    // p payload; 0 => free col
            if (i0 == 0) break;
            par = (par + 1) % 3;
        }

        // epilogue: settle duals (distinct rows => race-free), augment, clean slot
        if (used) {
            const double du = D - Dwin;                // == sum of deltas while used
            u_lds[pcol] += du;
            v_j -= du;
        }
        if (tid == 0) {
            u_lds[iroot] += D;                         // == sum of all deltas (D_end)
            dslot[par] = ~0ull;                        // the slot just consumed
            int j = juse;
            while (j) { const int jn = way_lds[j]; p_lds[j] = p_lds[jn]; j = jn; }
        }
        __syncthreads();
    }

    // ---- loss = 0.5 * sum_j ||dgm[p[j]-1] - dgm_x[j-1]||^2 (f32 diffs like ref) ----
    const int r = p_lds[col] - 1;
    const float2 a = dgm2[r];
    const float2 b = dgmx2[tid];
    const float fb = a.x - b.x;
    const float fd = a.y - b.y;
    double acc = (double)fb * (double)fb + (double)fd * (double)fd;
    #pragma unroll
    for (int m = 32; m >= 1; m >>= 1) acc += __shfl_xor(acc, m, 64);
    if (lane == 0) red8[wid] = acc;
    __syncthreads();
    if (tid == 0) {
        double s = 0.0;
        #pragma unroll
        for (int w = 0; w < 8; ++w) s += red8[w];
        out[0] = (float)(0.5 * s);
    }
}

extern "C" void kernel_launch(void* const* d_in, const int* in_sizes, int n_in,
                              void* d_out, int out_size, void* d_ws, size_t ws_size,
                              hipStream_t stream) {
    const float* dgm   = (const float*)d_in[0];
    const float* dgm_x = (const float*)d_in[1];
    float* out = (float*)d_out;
    tofu_solver<<<1, 512, 0, stream>>>(dgm, dgm_x, out);
}